// Round 12
// baseline (756.584 us; speedup 1.0000x reference)
//
#include <hip/hip_runtime.h>
#include <hip/hip_bf16.h>

#define NEG_SLOPE 0.2f

__device__ __forceinline__ unsigned short bf16bits(float f) {
    __hip_bfloat16 t = __float2bfloat16(f);
    return *reinterpret_cast<unsigned short*>(&t);
}

// Tiled GEMM node transform: block of 256 threads computes a [NB x FOUT] tile
// of h = x@W. Each thread: 4 nodes x 4 features in registers (16 FMA per k).
template <int FIN, int FOUT>
__global__ __launch_bounds__(256) void node_linear(
    const float* __restrict__ x, const float* __restrict__ W,
    const float* __restrict__ att_s, const float* __restrict__ att_d,
    __hip_bfloat16* __restrict__ h, float* __restrict__ a_s, float* __restrict__ a_d, int n)
{
    constexpr int FG = FOUT / 4;          // feature groups (4 features each)
    constexpr int NG = 256 / FG;          // node groups (4 nodes each)
    constexpr int NB = NG * 4;            // nodes per block
    constexpr int RS = FIN + 4;           // padded row stride
    __shared__ float xs[NB * RS];

    const int tid = threadIdx.x;
    const int base = blockIdx.x * NB;

    constexpr int CNT = NB * FIN / 4 / 256;
    #pragma unroll
    for (int i = 0; i < CNT; ++i) {
        int f4 = tid + 256 * i;
        int node = f4 / (FIN / 4);
        int kk = f4 % (FIN / 4);
        float4 v = make_float4(0.f, 0.f, 0.f, 0.f);
        if (base + node < n) v = *(const float4*)(x + (size_t)(base + node) * FIN + kk * 4);
        *(float4*)(xs + node * RS + kk * 4) = v;
    }
    __syncthreads();

    const int fg = tid % FG;
    const int ng = tid / FG;
    const float* wp = W + fg * 4;
    const float* xr0 = xs + (ng * 4 + 0) * RS;
    const float* xr1 = xs + (ng * 4 + 1) * RS;
    const float* xr2 = xs + (ng * 4 + 2) * RS;
    const float* xr3 = xs + (ng * 4 + 3) * RS;

    float a00=0,a01=0,a02=0,a03=0, a10=0,a11=0,a12=0,a13=0;
    float a20=0,a21=0,a22=0,a23=0, a30=0,a31=0,a32=0,a33=0;
    #pragma unroll 4
    for (int k = 0; k < FIN; ++k) {
        float4 w = *(const float4*)(wp + (size_t)k * FOUT);
        float x0 = xr0[k], x1 = xr1[k], x2 = xr2[k], x3 = xr3[k];
        a00 = fmaf(x0, w.x, a00); a01 = fmaf(x0, w.y, a01);
        a02 = fmaf(x0, w.z, a02); a03 = fmaf(x0, w.w, a03);
        a10 = fmaf(x1, w.x, a10); a11 = fmaf(x1, w.y, a11);
        a12 = fmaf(x1, w.z, a12); a13 = fmaf(x1, w.w, a13);
        a20 = fmaf(x2, w.x, a20); a21 = fmaf(x2, w.y, a21);
        a22 = fmaf(x2, w.z, a22); a23 = fmaf(x2, w.w, a23);
        a30 = fmaf(x3, w.x, a30); a31 = fmaf(x3, w.y, a31);
        a32 = fmaf(x3, w.z, a32); a33 = fmaf(x3, w.w, a33);
    }

    const float4 ats = *(const float4*)(att_s + fg * 4);
    const float4 atd = *(const float4*)(att_d + fg * 4);
    float acc[4][4] = {{a00,a01,a02,a03},{a10,a11,a12,a13},
                       {a20,a21,a22,a23},{a30,a31,a32,a33}};
    #pragma unroll
    for (int i = 0; i < 4; ++i) {
        int node = base + ng * 4 + i;
        float ps = acc[i][0]*ats.x + acc[i][1]*ats.y + acc[i][2]*ats.z + acc[i][3]*ats.w;
        float pd = acc[i][0]*atd.x + acc[i][1]*atd.y + acc[i][2]*atd.z + acc[i][3]*atd.w;
        #pragma unroll
        for (int o = FG / 2; o > 0; o >>= 1) {
            ps += __shfl_xor(ps, o);
            pd += __shfl_xor(pd, o);
        }
        if (fg == 0 && node < n) { a_s[node] = ps; a_d[node] = pd; }
        if (node < n) {
            unsigned w0 = (unsigned)bf16bits(acc[i][0]) | ((unsigned)bf16bits(acc[i][1]) << 16);
            unsigned w1 = (unsigned)bf16bits(acc[i][2]) | ((unsigned)bf16bits(acc[i][3]) << 16);
            uint2 pk; pk.x = w0; pk.y = w1;
            *reinterpret_cast<uint2*>(h + (size_t)node * FOUT + fg * 4) = pk;
        }
    }
}

// ---- CSR build: node hist -> scan -> LDS-staged multisplit -> per-SB sort ----
// Super-bucket (SB) = 512 consecutive dst nodes. packed = (dst&511)<<17 | src.

__global__ void node_hist(const int* __restrict__ edst, int E, int n,
                          int* __restrict__ cnt)
{
    int i = blockIdx.x * blockDim.x + threadIdx.x;
    const int Etot = E + n;
    if (i >= Etot) return;
    int d = (i < E) ? edst[i] : i - E;   // appended self-loops
    atomicAdd(cnt + d, 1);
}

__global__ __launch_bounds__(1024) void scan_block(
    const int* __restrict__ cnt, int n, int* __restrict__ row, int* __restrict__ partials)
{
    __shared__ int buf[1024];
    int gid = blockIdx.x * 1024 + threadIdx.x;
    int v = (gid < n) ? cnt[gid] : 0;
    buf[threadIdx.x] = v;
    __syncthreads();
    for (int off = 1; off < 1024; off <<= 1) {
        int t = (threadIdx.x >= off) ? buf[threadIdx.x - off] : 0;
        __syncthreads();
        buf[threadIdx.x] += t;
        __syncthreads();
    }
    if (gid < n) row[gid] = buf[threadIdx.x] - v;       // exclusive
    if (threadIdx.x == 1023) partials[blockIdx.x] = buf[1023];
}

__global__ __launch_bounds__(128) void scan_partials(int* __restrict__ partials, int nb)
{
    __shared__ int buf[128];
    int v = (threadIdx.x < nb) ? partials[threadIdx.x] : 0;
    buf[threadIdx.x] = v;
    __syncthreads();
    for (int off = 1; off < 128; off <<= 1) {
        int t = (threadIdx.x >= off) ? buf[threadIdx.x - off] : 0;
        __syncthreads();
        buf[threadIdx.x] += t;
        __syncthreads();
    }
    if (threadIdx.x < nb) partials[threadIdx.x] = buf[threadIdx.x] - v;  // exclusive
}

// Finalize exclusive scan; also emit row_end[node] = row[node] + cnt[node].
__global__ __launch_bounds__(1024) void scan_add(
    int* __restrict__ row, int n, const int* __restrict__ partials,
    const int* __restrict__ cnt, int* __restrict__ row_end)
{
    int gid = blockIdx.x * 1024 + threadIdx.x;
    if (gid < n) {
        int r = row[gid] + partials[blockIdx.x];
        row[gid] = r;
        row_end[gid] = r + cnt[gid];
    }
}

__global__ void init_sbcur(const int* __restrict__ row, int n, int nsb,
                           int* __restrict__ sbcur)
{
    int i = blockIdx.x * blockDim.x + threadIdx.x;
    if (i < nsb) sbcur[i] = row[i << 9];   // first node of SB i is < n
}

// LDS-staged binning: buffer 32 entries per SB, flush as contiguous 128B
// chunks at positions from sbcur. Eliminates cross-XCD line ping-pong.
#define MS_NSB_MAX 256
#define MS_CHUNK 32
__global__ __launch_bounds__(256) void multisplit(
    const int* __restrict__ esrc, const int* __restrict__ edst, int E, int n,
    int nsb, int* __restrict__ sbcur, int* __restrict__ packed1)
{
    __shared__ int lbuf[MS_NSB_MAX * MS_CHUNK];
    __shared__ int lcnt[MS_NSB_MAX];
    const int tid = threadIdx.x;
    const int wv = tid >> 6, lane = tid & 63;
    for (int i = tid; i < MS_NSB_MAX; i += 256) lcnt[i] = 0;
    __syncthreads();
    const int Etot = E + n;
    const int stride = gridDim.x * 256;
    for (int base = blockIdx.x * 256; base < Etot; base += stride) {
        int i = base + tid;
        bool pending = (i < Etot);
        int sb = 0, pk = 0;
        if (pending) {
            int s, d;
            if (i < E) { s = esrc[i]; d = edst[i]; }
            else       { s = d = i - E; }
            sb = d >> 9;
            pk = ((d & 511) << 17) | s;
        }
        while (__syncthreads_or(pending ? 1 : 0)) {
            if (pending) {
                int pos = atomicAdd(&lcnt[sb], 1);
                if (pos < MS_CHUNK) { lbuf[sb * MS_CHUNK + pos] = pk; pending = false; }
            }
            __syncthreads();
            for (int b = wv; b < nsb; b += 4) {   // each bucket owned by one wave
                int c = lcnt[b];
                if (c >= MS_CHUNK) {
                    int gp = 0;
                    if (lane == 0) gp = atomicAdd(&sbcur[b], MS_CHUNK);
                    gp = __shfl(gp, 0);
                    if (lane < MS_CHUNK) packed1[gp + lane] = lbuf[b * MS_CHUNK + lane];
                    if (lane == 0) lcnt[b] = 0;
                }
            }
            __syncthreads();
        }
    }
    // drain residual (<= MS_CHUNK per bucket)
    for (int b = wv; b < nsb; b += 4) {
        int c = lcnt[b];
        if (c > 0) {
            int gp = 0;
            if (lane == 0) gp = atomicAdd(&sbcur[b], c);
            gp = __shfl(gp, 0);
            if (lane < c) packed1[gp + lane] = lbuf[b * MS_CHUNK + lane];
        }
    }
}

// One block per SB: exact per-node scatter within the block-owned contiguous
// region (no cross-XCD sharing). LDS cursors from node-level scan.
__global__ __launch_bounds__(256) void sb_sort(
    const int* __restrict__ row, const int* __restrict__ packed1,
    int* __restrict__ col, int n, int Etot)
{
    const int sb = blockIdx.x;
    const int node0 = sb << 9;
    __shared__ int cur[512];
    for (int i = threadIdx.x; i < 512; i += 256) {
        int node = node0 + i;
        cur[i] = (node < n) ? row[node] : 0;
    }
    __syncthreads();
    const int lo = row[node0];
    const int nxt = node0 + 512;
    const int hi = (nxt < n) ? row[nxt] : Etot;
    for (int j = lo + threadIdx.x; j < hi; j += 256) {
        int p = packed1[j];
        int ld = ((unsigned)p) >> 17;
        int pos = atomicAdd(&cur[ld], 1);
        col[pos] = p & 0x1FFFF;
    }
}

// ---- Aggregation: FOUT lanes per node; 8-way unrolled gather loop for MLP.
template <int FOUT>
__global__ __launch_bounds__(256) void gat_aggregate(
    const int* __restrict__ row_end, const int* __restrict__ col,
    const float* __restrict__ a_s, const float* __restrict__ a_d,
    const __hip_bfloat16* __restrict__ h, const float* __restrict__ bias,
    float* __restrict__ outp, int n, int do_relu)
{
    constexpr int NPW = 64 / FOUT;
    const int gwave = (blockIdx.x * 256 + threadIdx.x) >> 6;
    const int lane = threadIdx.x & 63;
    const int node = gwave * NPW + lane / FOUT;
    const int f = lane % FOUT;
    if (node >= n) return;
    const int end = row_end[node];
    const int start = (node == 0) ? 0 : row_end[node - 1];
    const float adn = a_d[node];
    float acc = 0.f, den = 0.f;
    int j = start;
    for (; j + 8 <= end; j += 8) {
        int s0 = col[j+0], s1 = col[j+1], s2 = col[j+2], s3 = col[j+3];
        int s4 = col[j+4], s5 = col[j+5], s6 = col[j+6], s7 = col[j+7];
        float e0 = a_s[s0], e1 = a_s[s1], e2 = a_s[s2], e3 = a_s[s3];
        float e4 = a_s[s4], e5 = a_s[s5], e6 = a_s[s6], e7 = a_s[s7];
        float h0 = __bfloat162float(h[(size_t)s0 * FOUT + f]);
        float h1 = __bfloat162float(h[(size_t)s1 * FOUT + f]);
        float h2 = __bfloat162float(h[(size_t)s2 * FOUT + f]);
        float h3 = __bfloat162float(h[(size_t)s3 * FOUT + f]);
        float h4 = __bfloat162float(h[(size_t)s4 * FOUT + f]);
        float h5 = __bfloat162float(h[(size_t)s5 * FOUT + f]);
        float h6 = __bfloat162float(h[(size_t)s6 * FOUT + f]);
        float h7 = __bfloat162float(h[(size_t)s7 * FOUT + f]);
        e0 += adn; e1 += adn; e2 += adn; e3 += adn;
        e4 += adn; e5 += adn; e6 += adn; e7 += adn;
        e0 = (e0 > 0.f) ? e0 : NEG_SLOPE * e0;  e1 = (e1 > 0.f) ? e1 : NEG_SLOPE * e1;
        e2 = (e2 > 0.f) ? e2 : NEG_SLOPE * e2;  e3 = (e3 > 0.f) ? e3 : NEG_SLOPE * e3;
        e4 = (e4 > 0.f) ? e4 : NEG_SLOPE * e4;  e5 = (e5 > 0.f) ? e5 : NEG_SLOPE * e5;
        e6 = (e6 > 0.f) ? e6 : NEG_SLOPE * e6;  e7 = (e7 > 0.f) ? e7 : NEG_SLOPE * e7;
        float p0 = __expf(e0), p1 = __expf(e1), p2 = __expf(e2), p3 = __expf(e3);
        float p4 = __expf(e4), p5 = __expf(e5), p6 = __expf(e6), p7 = __expf(e7);
        den += ((p0 + p1) + (p2 + p3)) + ((p4 + p5) + (p6 + p7));
        acc = fmaf(p0, h0, acc); acc = fmaf(p1, h1, acc);
        acc = fmaf(p2, h2, acc); acc = fmaf(p3, h3, acc);
        acc = fmaf(p4, h4, acc); acc = fmaf(p5, h5, acc);
        acc = fmaf(p6, h6, acc); acc = fmaf(p7, h7, acc);
    }
    for (; j < end; ++j) {
        int s = col[j];
        float e = a_s[s] + adn;
        e = (e > 0.f) ? e : NEG_SLOPE * e;
        float p = __expf(e);
        den += p;
        acc = fmaf(p, __bfloat162float(h[(size_t)s * FOUT + f]), acc);
    }
    float v = acc / den + bias[f];             // self-loop guarantees den > 0
    if (do_relu) v = fmaxf(v, 0.f);
    outp[(size_t)node * FOUT + f] = v;
}

extern "C" void kernel_launch(void* const* d_in, const int* in_sizes, int n_in,
                              void* d_out, int out_size, void* d_ws, size_t ws_size,
                              hipStream_t stream)
{
    const float* x   = (const float*)d_in[0];
    const int* eidx  = (const int*)d_in[1];
    const float* W1  = (const float*)d_in[2];
    const float* as1 = (const float*)d_in[3];
    const float* ad1 = (const float*)d_in[4];
    const float* b1  = (const float*)d_in[5];
    const float* W2  = (const float*)d_in[6];
    const float* as2 = (const float*)d_in[7];
    const float* ad2 = (const float*)d_in[8];
    const float* b2  = (const float*)d_in[9];
    const float* W3  = (const float*)d_in[10];
    const float* as3 = (const float*)d_in[11];
    const float* ad3 = (const float*)d_in[12];
    const float* b3  = (const float*)d_in[13];

    const int fhid = in_sizes[3];        // 64
    const int fin  = in_sizes[2] / fhid; // 128
    const int fo3  = in_sizes[11];       // 32
    const int n    = in_sizes[0] / fin;  // 100000
    const int E    = in_sizes[1] / 2;    // 1,600,000
    const int Etot = E + n;
    const int nsb  = (n + 511) >> 9;     // 196 super-buckets

    const int* esrc = eidx;
    const int* edst = eidx + E;

    float* out = (float*)d_out;               // [n, fo3]
    float* h1  = out + (size_t)n * fo3;       // [n, fhid]
    float* h2  = h1 + (size_t)n * fhid;       // [n, fhid]

    // ws: cnt[n] | row[n] | row_end[n] | partials[128] | sbcur[256] |
    //     packed1[Etot] | col[Etot] | h_bf16[n*fhid] | a_s[n] | a_d[n]
    int* cnt      = (int*)d_ws;
    int* row      = cnt + n;
    int* row_end  = row + n;
    int* partials = row_end + n;
    int* sbcur    = partials + 128;
    int* packed1  = sbcur + 256;
    int* col      = packed1 + Etot;
    __hip_bfloat16* h = (__hip_bfloat16*)(col + Etot);
    float* a_s    = (float*)(h + (size_t)n * fhid);
    float* a_d    = a_s + n;

    const int EB = (Etot + 255) / 256;
    const int nb = (n + 1023) / 1024;    // 98 <= 128

    // ---- CSR build (shared by all layers) ----
    hipMemsetAsync(cnt, 0, (size_t)n * 4, stream);
    node_hist<<<EB, 256, 0, stream>>>(edst, E, n, cnt);
    scan_block<<<nb, 1024, 0, stream>>>(cnt, n, row, partials);
    scan_partials<<<1, 128, 0, stream>>>(partials, nb);
    scan_add<<<nb, 1024, 0, stream>>>(row, n, partials, cnt, row_end);
    init_sbcur<<<(nsb + 255) / 256, 256, 0, stream>>>(row, n, nsb, sbcur);
    multisplit<<<512, 256, 0, stream>>>(esrc, edst, E, n, nsb, sbcur, packed1);
    sb_sort<<<nsb, 256, 0, stream>>>(row, packed1, col, n, Etot);

    const int NLB64  = (n + 63) / 64;
    const int NLB128 = (n + 127) / 128;
    const int AGG64 = (n + 3) / 4;
    const int AGG32 = (n + 7) / 8;

    // ---- Layer 1: x[128] -> h1[64], relu ----
    node_linear<128, 64><<<NLB64, 256, 0, stream>>>(x, W1, as1, ad1, h, a_s, a_d, n);
    gat_aggregate<64><<<AGG64, 256, 0, stream>>>(row_end, col, a_s, a_d, h, b1, h1, n, 1);

    // ---- Layer 2: h1[64] -> h2[64], relu ----
    node_linear<64, 64><<<NLB64, 256, 0, stream>>>(h1, W2, as2, ad2, h, a_s, a_d, n);
    gat_aggregate<64><<<AGG64, 256, 0, stream>>>(row_end, col, a_s, a_d, h, b2, h2, n, 1);

    // ---- Layer 3: h2[64] -> out[32], no relu ----
    node_linear<64, 32><<<NLB128, 256, 0, stream>>>(h2, W3, as3, ad3, h, a_s, a_d, n);
    gat_aggregate<32><<<AGG32, 256, 0, stream>>>(row_end, col, a_s, a_d, h, b3, out, n, 0);
}

// Round 13
// 390.607 us; speedup vs baseline: 1.9369x; 1.9369x over previous
//
#include <hip/hip_runtime.h>
#include <hip/hip_bf16.h>

#define NEG_SLOPE 0.2f

__device__ __forceinline__ unsigned short bf16bits(float f) {
    __hip_bfloat16 t = __float2bfloat16(f);
    return *reinterpret_cast<unsigned short*>(&t);
}

// Tiled GEMM node transform: block of 256 threads computes a [NB x FOUT] tile
// of h = x@W. Each thread: 4 nodes x 4 features in registers (16 FMA per k).
template <int FIN, int FOUT>
__global__ __launch_bounds__(256) void node_linear(
    const float* __restrict__ x, const float* __restrict__ W,
    const float* __restrict__ att_s, const float* __restrict__ att_d,
    __hip_bfloat16* __restrict__ h, float* __restrict__ a_s, float* __restrict__ a_d, int n)
{
    constexpr int FG = FOUT / 4;          // feature groups (4 features each)
    constexpr int NG = 256 / FG;          // node groups (4 nodes each)
    constexpr int NB = NG * 4;            // nodes per block
    constexpr int RS = FIN + 4;           // padded row stride
    __shared__ float xs[NB * RS];

    const int tid = threadIdx.x;
    const int base = blockIdx.x * NB;

    constexpr int CNT = NB * FIN / 4 / 256;
    #pragma unroll
    for (int i = 0; i < CNT; ++i) {
        int f4 = tid + 256 * i;
        int node = f4 / (FIN / 4);
        int kk = f4 % (FIN / 4);
        float4 v = make_float4(0.f, 0.f, 0.f, 0.f);
        if (base + node < n) v = *(const float4*)(x + (size_t)(base + node) * FIN + kk * 4);
        *(float4*)(xs + node * RS + kk * 4) = v;
    }
    __syncthreads();

    const int fg = tid % FG;
    const int ng = tid / FG;
    const float* wp = W + fg * 4;
    const float* xr0 = xs + (ng * 4 + 0) * RS;
    const float* xr1 = xs + (ng * 4 + 1) * RS;
    const float* xr2 = xs + (ng * 4 + 2) * RS;
    const float* xr3 = xs + (ng * 4 + 3) * RS;

    float a00=0,a01=0,a02=0,a03=0, a10=0,a11=0,a12=0,a13=0;
    float a20=0,a21=0,a22=0,a23=0, a30=0,a31=0,a32=0,a33=0;
    #pragma unroll 4
    for (int k = 0; k < FIN; ++k) {
        float4 w = *(const float4*)(wp + (size_t)k * FOUT);
        float x0 = xr0[k], x1 = xr1[k], x2 = xr2[k], x3 = xr3[k];
        a00 = fmaf(x0, w.x, a00); a01 = fmaf(x0, w.y, a01);
        a02 = fmaf(x0, w.z, a02); a03 = fmaf(x0, w.w, a03);
        a10 = fmaf(x1, w.x, a10); a11 = fmaf(x1, w.y, a11);
        a12 = fmaf(x1, w.z, a12); a13 = fmaf(x1, w.w, a13);
        a20 = fmaf(x2, w.x, a20); a21 = fmaf(x2, w.y, a21);
        a22 = fmaf(x2, w.z, a22); a23 = fmaf(x2, w.w, a23);
        a30 = fmaf(x3, w.x, a30); a31 = fmaf(x3, w.y, a31);
        a32 = fmaf(x3, w.z, a32); a33 = fmaf(x3, w.w, a33);
    }

    const float4 ats = *(const float4*)(att_s + fg * 4);
    const float4 atd = *(const float4*)(att_d + fg * 4);
    float acc[4][4] = {{a00,a01,a02,a03},{a10,a11,a12,a13},
                       {a20,a21,a22,a23},{a30,a31,a32,a33}};
    #pragma unroll
    for (int i = 0; i < 4; ++i) {
        int node = base + ng * 4 + i;
        float ps = acc[i][0]*ats.x + acc[i][1]*ats.y + acc[i][2]*ats.z + acc[i][3]*ats.w;
        float pd = acc[i][0]*atd.x + acc[i][1]*atd.y + acc[i][2]*atd.z + acc[i][3]*atd.w;
        #pragma unroll
        for (int o = FG / 2; o > 0; o >>= 1) {
            ps += __shfl_xor(ps, o);
            pd += __shfl_xor(pd, o);
        }
        if (fg == 0 && node < n) { a_s[node] = ps; a_d[node] = pd; }
        if (node < n) {
            unsigned w0 = (unsigned)bf16bits(acc[i][0]) | ((unsigned)bf16bits(acc[i][1]) << 16);
            unsigned w1 = (unsigned)bf16bits(acc[i][2]) | ((unsigned)bf16bits(acc[i][3]) << 16);
            uint2 pk; pk.x = w0; pk.y = w1;
            *reinterpret_cast<uint2*>(h + (size_t)node * FOUT + fg * 4) = pk;
        }
    }
}

// ---- CSR build: node hist -> scan -> per-chunk SB bin -> per-SB sort ----
// Super-bucket (SB) = 512 consecutive dst nodes. packed = (dst&511)<<17 | src.

__global__ void node_hist(const int* __restrict__ edst, int E, int n,
                          int* __restrict__ cnt)
{
    int i = blockIdx.x * blockDim.x + threadIdx.x;
    const int Etot = E + n;
    if (i >= Etot) return;
    int d = (i < E) ? edst[i] : i - E;   // appended self-loops
    atomicAdd(cnt + d, 1);
}

__global__ __launch_bounds__(1024) void scan_block(
    const int* __restrict__ cnt, int n, int* __restrict__ row, int* __restrict__ partials)
{
    __shared__ int buf[1024];
    int gid = blockIdx.x * 1024 + threadIdx.x;
    int v = (gid < n) ? cnt[gid] : 0;
    buf[threadIdx.x] = v;
    __syncthreads();
    for (int off = 1; off < 1024; off <<= 1) {
        int t = (threadIdx.x >= off) ? buf[threadIdx.x - off] : 0;
        __syncthreads();
        buf[threadIdx.x] += t;
        __syncthreads();
    }
    if (gid < n) row[gid] = buf[threadIdx.x] - v;       // exclusive
    if (threadIdx.x == 1023) partials[blockIdx.x] = buf[1023];
}

__global__ __launch_bounds__(128) void scan_partials(int* __restrict__ partials, int nb)
{
    __shared__ int buf[128];
    int v = (threadIdx.x < nb) ? partials[threadIdx.x] : 0;
    buf[threadIdx.x] = v;
    __syncthreads();
    for (int off = 1; off < 128; off <<= 1) {
        int t = (threadIdx.x >= off) ? buf[threadIdx.x - off] : 0;
        __syncthreads();
        buf[threadIdx.x] += t;
        __syncthreads();
    }
    if (threadIdx.x < nb) partials[threadIdx.x] = buf[threadIdx.x] - v;  // exclusive
}

// Finalize exclusive scan; also emit row_end[node] = row[node] + cnt[node].
__global__ __launch_bounds__(1024) void scan_add(
    int* __restrict__ row, int n, const int* __restrict__ partials,
    const int* __restrict__ cnt, int* __restrict__ row_end)
{
    int gid = blockIdx.x * 1024 + threadIdx.x;
    if (gid < n) {
        int r = row[gid] + partials[blockIdx.x];
        row[gid] = r;
        row_end[gid] = r + cnt[gid];
    }
}

__global__ void init_sbcur(const int* __restrict__ row, int n, int nsb,
                           int* __restrict__ sbcur)
{
    int i = blockIdx.x * blockDim.x + threadIdx.x;
    if (i < nsb) sbcur[i] = row[i << 9];   // first node of SB i is < n
}

// Stateless per-chunk SB binning: each block owns CHUNK edges. (1) stage to
// LDS + LDS histogram of 196 SBs; (2) ONE global atomicAdd per non-empty SB
// reserves a contiguous run; (3) scatter from LDS to the reserved run.
// Runs (~21 entries) keep lines resident in the block's own XCD L2.
#define CB_CHUNK 4096
#define CB_NSB_MAX 256
__global__ __launch_bounds__(256) void chunk_bin(
    const int* __restrict__ esrc, const int* __restrict__ edst, int E, int n,
    int nsb, int* __restrict__ sbcur, int* __restrict__ packed1)
{
    __shared__ int pk[CB_CHUNK];
    __shared__ unsigned short sbv[CB_CHUNK];
    __shared__ int hist[CB_NSB_MAX];
    __shared__ int gbase[CB_NSB_MAX];
    const int tid = threadIdx.x;
    const int i0 = blockIdx.x * CB_CHUNK;
    const int Etot = E + n;

    hist[tid] = 0;
    __syncthreads();

    for (int j = tid; j < CB_CHUNK; j += 256) {
        int i = i0 + j;
        if (i < Etot) {
            int s, d;
            if (i < E) { s = esrc[i]; d = edst[i]; }
            else       { s = d = i - E; }          // appended self-loops
            int sb = d >> 9;
            pk[j] = ((d & 511) << 17) | s;
            sbv[j] = (unsigned short)sb;
            atomicAdd(&hist[sb], 1);
        } else {
            sbv[j] = 0xFFFFu;
        }
    }
    __syncthreads();

    if (tid < nsb && hist[tid] > 0)
        gbase[tid] = atomicAdd(&sbcur[tid], hist[tid]);
    hist[tid] = 0;                         // reuse as local cursor
    __syncthreads();

    for (int j = tid; j < CB_CHUNK; j += 256) {
        unsigned short sb = sbv[j];
        if (sb != 0xFFFFu) {
            int pos = gbase[sb] + atomicAdd(&hist[sb], 1);
            packed1[pos] = pk[j];
        }
    }
}

// One block per SB: exact per-node scatter within the block-owned contiguous
// region (no cross-XCD sharing). LDS cursors from node-level scan.
__global__ __launch_bounds__(256) void sb_sort(
    const int* __restrict__ row, const int* __restrict__ packed1,
    int* __restrict__ col, int n, int Etot)
{
    const int sb = blockIdx.x;
    const int node0 = sb << 9;
    __shared__ int cur[512];
    for (int i = threadIdx.x; i < 512; i += 256) {
        int node = node0 + i;
        cur[i] = (node < n) ? row[node] : 0;
    }
    __syncthreads();
    const int lo = row[node0];
    const int nxt = node0 + 512;
    const int hi = (nxt < n) ? row[nxt] : Etot;
    for (int j = lo + threadIdx.x; j < hi; j += 256) {
        int p = packed1[j];
        int ld = ((unsigned)p) >> 17;
        int pos = atomicAdd(&cur[ld], 1);
        col[pos] = p & 0x1FFFF;
    }
}

// ---- Aggregation: FOUT lanes per node; 8-way unrolled gather loop for MLP.
template <int FOUT>
__global__ __launch_bounds__(256) void gat_aggregate(
    const int* __restrict__ row_end, const int* __restrict__ col,
    const float* __restrict__ a_s, const float* __restrict__ a_d,
    const __hip_bfloat16* __restrict__ h, const float* __restrict__ bias,
    float* __restrict__ outp, int n, int do_relu)
{
    constexpr int NPW = 64 / FOUT;
    const int gwave = (blockIdx.x * 256 + threadIdx.x) >> 6;
    const int lane = threadIdx.x & 63;
    const int node = gwave * NPW + lane / FOUT;
    const int f = lane % FOUT;
    if (node >= n) return;
    const int end = row_end[node];
    const int start = (node == 0) ? 0 : row_end[node - 1];
    const float adn = a_d[node];
    float acc = 0.f, den = 0.f;
    int j = start;
    for (; j + 8 <= end; j += 8) {
        int s0 = col[j+0], s1 = col[j+1], s2 = col[j+2], s3 = col[j+3];
        int s4 = col[j+4], s5 = col[j+5], s6 = col[j+6], s7 = col[j+7];
        float e0 = a_s[s0], e1 = a_s[s1], e2 = a_s[s2], e3 = a_s[s3];
        float e4 = a_s[s4], e5 = a_s[s5], e6 = a_s[s6], e7 = a_s[s7];
        float h0 = __bfloat162float(h[(size_t)s0 * FOUT + f]);
        float h1 = __bfloat162float(h[(size_t)s1 * FOUT + f]);
        float h2 = __bfloat162float(h[(size_t)s2 * FOUT + f]);
        float h3 = __bfloat162float(h[(size_t)s3 * FOUT + f]);
        float h4 = __bfloat162float(h[(size_t)s4 * FOUT + f]);
        float h5 = __bfloat162float(h[(size_t)s5 * FOUT + f]);
        float h6 = __bfloat162float(h[(size_t)s6 * FOUT + f]);
        float h7 = __bfloat162float(h[(size_t)s7 * FOUT + f]);
        e0 += adn; e1 += adn; e2 += adn; e3 += adn;
        e4 += adn; e5 += adn; e6 += adn; e7 += adn;
        e0 = (e0 > 0.f) ? e0 : NEG_SLOPE * e0;  e1 = (e1 > 0.f) ? e1 : NEG_SLOPE * e1;
        e2 = (e2 > 0.f) ? e2 : NEG_SLOPE * e2;  e3 = (e3 > 0.f) ? e3 : NEG_SLOPE * e3;
        e4 = (e4 > 0.f) ? e4 : NEG_SLOPE * e4;  e5 = (e5 > 0.f) ? e5 : NEG_SLOPE * e5;
        e6 = (e6 > 0.f) ? e6 : NEG_SLOPE * e6;  e7 = (e7 > 0.f) ? e7 : NEG_SLOPE * e7;
        float p0 = __expf(e0), p1 = __expf(e1), p2 = __expf(e2), p3 = __expf(e3);
        float p4 = __expf(e4), p5 = __expf(e5), p6 = __expf(e6), p7 = __expf(e7);
        den += ((p0 + p1) + (p2 + p3)) + ((p4 + p5) + (p6 + p7));
        acc = fmaf(p0, h0, acc); acc = fmaf(p1, h1, acc);
        acc = fmaf(p2, h2, acc); acc = fmaf(p3, h3, acc);
        acc = fmaf(p4, h4, acc); acc = fmaf(p5, h5, acc);
        acc = fmaf(p6, h6, acc); acc = fmaf(p7, h7, acc);
    }
    for (; j < end; ++j) {
        int s = col[j];
        float e = a_s[s] + adn;
        e = (e > 0.f) ? e : NEG_SLOPE * e;
        float p = __expf(e);
        den += p;
        acc = fmaf(p, __bfloat162float(h[(size_t)s * FOUT + f]), acc);
    }
    float v = acc / den + bias[f];             // self-loop guarantees den > 0
    if (do_relu) v = fmaxf(v, 0.f);
    outp[(size_t)node * FOUT + f] = v;
}

extern "C" void kernel_launch(void* const* d_in, const int* in_sizes, int n_in,
                              void* d_out, int out_size, void* d_ws, size_t ws_size,
                              hipStream_t stream)
{
    const float* x   = (const float*)d_in[0];
    const int* eidx  = (const int*)d_in[1];
    const float* W1  = (const float*)d_in[2];
    const float* as1 = (const float*)d_in[3];
    const float* ad1 = (const float*)d_in[4];
    const float* b1  = (const float*)d_in[5];
    const float* W2  = (const float*)d_in[6];
    const float* as2 = (const float*)d_in[7];
    const float* ad2 = (const float*)d_in[8];
    const float* b2  = (const float*)d_in[9];
    const float* W3  = (const float*)d_in[10];
    const float* as3 = (const float*)d_in[11];
    const float* ad3 = (const float*)d_in[12];
    const float* b3  = (const float*)d_in[13];

    const int fhid = in_sizes[3];        // 64
    const int fin  = in_sizes[2] / fhid; // 128
    const int fo3  = in_sizes[11];       // 32
    const int n    = in_sizes[0] / fin;  // 100000
    const int E    = in_sizes[1] / 2;    // 1,600,000
    const int Etot = E + n;
    const int nsb  = (n + 511) >> 9;     // 196 super-buckets

    const int* esrc = eidx;
    const int* edst = eidx + E;

    float* out = (float*)d_out;               // [n, fo3]
    float* h1  = out + (size_t)n * fo3;       // [n, fhid]
    float* h2  = h1 + (size_t)n * fhid;       // [n, fhid]

    // ws: cnt[n] | row[n] | row_end[n] | partials[128] | sbcur[256] |
    //     packed1[Etot] | col[Etot] | h_bf16[n*fhid] | a_s[n] | a_d[n]
    int* cnt      = (int*)d_ws;
    int* row      = cnt + n;
    int* row_end  = row + n;
    int* partials = row_end + n;
    int* sbcur    = partials + 128;
    int* packed1  = sbcur + 256;
    int* col      = packed1 + Etot;
    __hip_bfloat16* h = (__hip_bfloat16*)(col + Etot);
    float* a_s    = (float*)(h + (size_t)n * fhid);
    float* a_d    = a_s + n;

    const int EB = (Etot + 255) / 256;
    const int nb = (n + 1023) / 1024;    // 98 <= 128
    const int nchunks = (Etot + CB_CHUNK - 1) / CB_CHUNK;

    // ---- CSR build (shared by all layers) ----
    hipMemsetAsync(cnt, 0, (size_t)n * 4, stream);
    node_hist<<<EB, 256, 0, stream>>>(edst, E, n, cnt);
    scan_block<<<nb, 1024, 0, stream>>>(cnt, n, row, partials);
    scan_partials<<<1, 128, 0, stream>>>(partials, nb);
    scan_add<<<nb, 1024, 0, stream>>>(row, n, partials, cnt, row_end);
    init_sbcur<<<(nsb + 255) / 256, 256, 0, stream>>>(row, n, nsb, sbcur);
    chunk_bin<<<nchunks, 256, 0, stream>>>(esrc, edst, E, n, nsb, sbcur, packed1);
    sb_sort<<<nsb, 256, 0, stream>>>(row, packed1, col, n, Etot);

    const int NLB64  = (n + 63) / 64;
    const int NLB128 = (n + 127) / 128;
    const int AGG64 = (n + 3) / 4;
    const int AGG32 = (n + 7) / 8;

    // ---- Layer 1: x[128] -> h1[64], relu ----
    node_linear<128, 64><<<NLB64, 256, 0, stream>>>(x, W1, as1, ad1, h, a_s, a_d, n);
    gat_aggregate<64><<<AGG64, 256, 0, stream>>>(row_end, col, a_s, a_d, h, b1, h1, n, 1);

    // ---- Layer 2: h1[64] -> h2[64], relu ----
    node_linear<64, 64><<<NLB64, 256, 0, stream>>>(h1, W2, as2, ad2, h, a_s, a_d, n);
    gat_aggregate<64><<<AGG64, 256, 0, stream>>>(row_end, col, a_s, a_d, h, b2, h2, n, 1);

    // ---- Layer 3: h2[64] -> out[32], no relu ----
    node_linear<64, 32><<<NLB128, 256, 0, stream>>>(h2, W3, as3, ad3, h, a_s, a_d, n);
    gat_aggregate<32><<<AGG32, 256, 0, stream>>>(row_end, col, a_s, a_d, h, b3, out, n, 0);
}

// Round 14
// 353.162 us; speedup vs baseline: 2.1423x; 1.1060x over previous
//
#include <hip/hip_runtime.h>
#include <hip/hip_bf16.h>

#define NEG_SLOPE 0.2f

__device__ __forceinline__ unsigned short bf16bits(float f) {
    __hip_bfloat16 t = __float2bfloat16(f);
    return *reinterpret_cast<unsigned short*>(&t);
}

// Tiled GEMM node transform: block of 256 threads computes a [NB x FOUT] tile
// of h = x@W. Each thread: 4 nodes x 4 features in registers (16 FMA per k).
template <int FIN, int FOUT>
__global__ __launch_bounds__(256) void node_linear(
    const float* __restrict__ x, const float* __restrict__ W,
    const float* __restrict__ att_s, const float* __restrict__ att_d,
    __hip_bfloat16* __restrict__ h, float* __restrict__ a_s, float* __restrict__ a_d, int n)
{
    constexpr int FG = FOUT / 4;          // feature groups (4 features each)
    constexpr int NG = 256 / FG;          // node groups (4 nodes each)
    constexpr int NB = NG * 4;            // nodes per block
    constexpr int RS = FIN + 4;           // padded row stride
    __shared__ float xs[NB * RS];

    const int tid = threadIdx.x;
    const int base = blockIdx.x * NB;

    constexpr int CNT = NB * FIN / 4 / 256;
    #pragma unroll
    for (int i = 0; i < CNT; ++i) {
        int f4 = tid + 256 * i;
        int node = f4 / (FIN / 4);
        int kk = f4 % (FIN / 4);
        float4 v = make_float4(0.f, 0.f, 0.f, 0.f);
        if (base + node < n) v = *(const float4*)(x + (size_t)(base + node) * FIN + kk * 4);
        *(float4*)(xs + node * RS + kk * 4) = v;
    }
    __syncthreads();

    const int fg = tid % FG;
    const int ng = tid / FG;
    const float* wp = W + fg * 4;
    const float* xr0 = xs + (ng * 4 + 0) * RS;
    const float* xr1 = xs + (ng * 4 + 1) * RS;
    const float* xr2 = xs + (ng * 4 + 2) * RS;
    const float* xr3 = xs + (ng * 4 + 3) * RS;

    float a00=0,a01=0,a02=0,a03=0, a10=0,a11=0,a12=0,a13=0;
    float a20=0,a21=0,a22=0,a23=0, a30=0,a31=0,a32=0,a33=0;
    #pragma unroll 4
    for (int k = 0; k < FIN; ++k) {
        float4 w = *(const float4*)(wp + (size_t)k * FOUT);
        float x0 = xr0[k], x1 = xr1[k], x2 = xr2[k], x3 = xr3[k];
        a00 = fmaf(x0, w.x, a00); a01 = fmaf(x0, w.y, a01);
        a02 = fmaf(x0, w.z, a02); a03 = fmaf(x0, w.w, a03);
        a10 = fmaf(x1, w.x, a10); a11 = fmaf(x1, w.y, a11);
        a12 = fmaf(x1, w.z, a12); a13 = fmaf(x1, w.w, a13);
        a20 = fmaf(x2, w.x, a20); a21 = fmaf(x2, w.y, a21);
        a22 = fmaf(x2, w.z, a22); a23 = fmaf(x2, w.w, a23);
        a30 = fmaf(x3, w.x, a30); a31 = fmaf(x3, w.y, a31);
        a32 = fmaf(x3, w.z, a32); a33 = fmaf(x3, w.w, a33);
    }

    const float4 ats = *(const float4*)(att_s + fg * 4);
    const float4 atd = *(const float4*)(att_d + fg * 4);
    float acc[4][4] = {{a00,a01,a02,a03},{a10,a11,a12,a13},
                       {a20,a21,a22,a23},{a30,a31,a32,a33}};
    #pragma unroll
    for (int i = 0; i < 4; ++i) {
        int node = base + ng * 4 + i;
        float ps = acc[i][0]*ats.x + acc[i][1]*ats.y + acc[i][2]*ats.z + acc[i][3]*ats.w;
        float pd = acc[i][0]*atd.x + acc[i][1]*atd.y + acc[i][2]*atd.z + acc[i][3]*atd.w;
        #pragma unroll
        for (int o = FG / 2; o > 0; o >>= 1) {
            ps += __shfl_xor(ps, o);
            pd += __shfl_xor(pd, o);
        }
        if (fg == 0 && node < n) { a_s[node] = ps; a_d[node] = pd; }
        if (node < n) {
            unsigned w0 = (unsigned)bf16bits(acc[i][0]) | ((unsigned)bf16bits(acc[i][1]) << 16);
            unsigned w1 = (unsigned)bf16bits(acc[i][2]) | ((unsigned)bf16bits(acc[i][3]) << 16);
            uint2 pk; pk.x = w0; pk.y = w1;
            *reinterpret_cast<uint2*>(h + (size_t)node * FOUT + fg * 4) = pk;
        }
    }
}

// ---- CSR build: node hist -> scan -> per-chunk SB bin -> per-SB sort ----
// Super-bucket (SB) = 512 consecutive dst nodes. packed = (dst&511)<<17 | src.

__global__ void node_hist(const int* __restrict__ edst, int E, int n,
                          int* __restrict__ cnt)
{
    int i = blockIdx.x * blockDim.x + threadIdx.x;
    const int Etot = E + n;
    if (i >= Etot) return;
    int d = (i < E) ? edst[i] : i - E;   // appended self-loops
    atomicAdd(cnt + d, 1);
}

__global__ __launch_bounds__(1024) void scan_block(
    const int* __restrict__ cnt, int n, int* __restrict__ row, int* __restrict__ partials)
{
    __shared__ int buf[1024];
    int gid = blockIdx.x * 1024 + threadIdx.x;
    int v = (gid < n) ? cnt[gid] : 0;
    buf[threadIdx.x] = v;
    __syncthreads();
    for (int off = 1; off < 1024; off <<= 1) {
        int t = (threadIdx.x >= off) ? buf[threadIdx.x - off] : 0;
        __syncthreads();
        buf[threadIdx.x] += t;
        __syncthreads();
    }
    if (gid < n) row[gid] = buf[threadIdx.x] - v;       // exclusive
    if (threadIdx.x == 1023) partials[blockIdx.x] = buf[1023];
}

__global__ __launch_bounds__(128) void scan_partials(int* __restrict__ partials, int nb)
{
    __shared__ int buf[128];
    int v = (threadIdx.x < nb) ? partials[threadIdx.x] : 0;
    buf[threadIdx.x] = v;
    __syncthreads();
    for (int off = 1; off < 128; off <<= 1) {
        int t = (threadIdx.x >= off) ? buf[threadIdx.x - off] : 0;
        __syncthreads();
        buf[threadIdx.x] += t;
        __syncthreads();
    }
    if (threadIdx.x < nb) partials[threadIdx.x] = buf[threadIdx.x] - v;  // exclusive
}

// Finalize exclusive scan; also emit row_end[node] = row[node] + cnt[node].
__global__ __launch_bounds__(1024) void scan_add(
    int* __restrict__ row, int n, const int* __restrict__ partials,
    const int* __restrict__ cnt, int* __restrict__ row_end)
{
    int gid = blockIdx.x * 1024 + threadIdx.x;
    if (gid < n) {
        int r = row[gid] + partials[blockIdx.x];
        row[gid] = r;
        row_end[gid] = r + cnt[gid];
    }
}

__global__ void init_sbcur(const int* __restrict__ row, int n, int nsb,
                           int* __restrict__ sbcur)
{
    int i = blockIdx.x * blockDim.x + threadIdx.x;
    if (i < nsb) sbcur[i] = row[i << 9];   // first node of SB i is < n
}

// Stateless per-chunk SB binning: each block owns CHUNK edges. (1) stage to
// LDS + LDS histogram of 196 SBs; (2) ONE global atomicAdd per non-empty SB
// reserves a contiguous run; (3) scatter from LDS to the reserved run.
#define CB_CHUNK 4096
#define CB_NSB_MAX 256
__global__ __launch_bounds__(256) void chunk_bin(
    const int* __restrict__ esrc, const int* __restrict__ edst, int E, int n,
    int nsb, int* __restrict__ sbcur, int* __restrict__ packed1)
{
    __shared__ int pk[CB_CHUNK];
    __shared__ unsigned short sbv[CB_CHUNK];
    __shared__ int hist[CB_NSB_MAX];
    __shared__ int gbase[CB_NSB_MAX];
    const int tid = threadIdx.x;
    const int i0 = blockIdx.x * CB_CHUNK;
    const int Etot = E + n;

    hist[tid] = 0;
    __syncthreads();

    for (int j = tid; j < CB_CHUNK; j += 256) {
        int i = i0 + j;
        if (i < Etot) {
            int s, d;
            if (i < E) { s = esrc[i]; d = edst[i]; }
            else       { s = d = i - E; }          // appended self-loops
            int sb = d >> 9;
            pk[j] = ((d & 511) << 17) | s;
            sbv[j] = (unsigned short)sb;
            atomicAdd(&hist[sb], 1);
        } else {
            sbv[j] = 0xFFFFu;
        }
    }
    __syncthreads();

    if (tid < nsb && hist[tid] > 0)
        gbase[tid] = atomicAdd(&sbcur[tid], hist[tid]);
    hist[tid] = 0;                         // reuse as local cursor
    __syncthreads();

    for (int j = tid; j < CB_CHUNK; j += 256) {
        unsigned short sb = sbv[j];
        if (sb != 0xFFFFu) {
            int pos = gbase[sb] + atomicAdd(&hist[sb], 1);
            packed1[pos] = pk[j];
        }
    }
}

// One block per SB: exact per-node scatter within the block-owned contiguous
// region (no cross-XCD sharing). LDS cursors from node-level scan.
__global__ __launch_bounds__(256) void sb_sort(
    const int* __restrict__ row, const int* __restrict__ packed1,
    int* __restrict__ col, int n, int Etot)
{
    const int sb = blockIdx.x;
    const int node0 = sb << 9;
    __shared__ int cur[512];
    for (int i = threadIdx.x; i < 512; i += 256) {
        int node = node0 + i;
        cur[i] = (node < n) ? row[node] : 0;
    }
    __syncthreads();
    const int lo = row[node0];
    const int nxt = node0 + 512;
    const int hi = (nxt < n) ? row[nxt] : Etot;
    for (int j = lo + threadIdx.x; j < hi; j += 256) {
        int p = packed1[j];
        int ld = ((unsigned)p) >> 17;
        int pos = atomicAdd(&cur[ld], 1);
        col[pos] = p & 0x1FFFF;
    }
}

// ---- Aggregation: FOUT lanes per node. Lane-split scores: lane l computes
// the score for edge j+(l&7) only (1 col load + 1 a_s load + 1 exp per 8
// edges), then (src,p) broadcast wave-wide via shuffles. Masked 8-wide tail
// (clamped index, p=0) replaces the scalar remainder loop.
template <int FOUT>
__global__ __launch_bounds__(256) void gat_aggregate(
    const int* __restrict__ row_end, const int* __restrict__ col,
    const float* __restrict__ a_s, const float* __restrict__ a_d,
    const __hip_bfloat16* __restrict__ h, const float* __restrict__ bias,
    float* __restrict__ outp, int n, int do_relu)
{
    constexpr int NPW = 64 / FOUT;
    const int gwave = (blockIdx.x * 256 + threadIdx.x) >> 6;
    const int lane = threadIdx.x & 63;
    const int node = gwave * NPW + lane / FOUT;
    const int f = lane % FOUT;
    if (node >= n) return;
    const int end = row_end[node];
    const int start = (node == 0) ? 0 : row_end[node - 1];
    const float adn = a_d[node];
    // shuffle group base: lanes of this node's sub-wave (0 for FOUT=64;
    // 0/32 halves for FOUT=32). Shuffles never cross sub-wave boundaries.
    const int egrp = (FOUT == 64) ? 0 : (lane & 32);
    float acc = 0.f, den = 0.f;
    for (int j = start; j < end; j += 8) {
        int k_idx = j + (lane & 7);
        int clamped = (k_idx < end) ? k_idx : (end - 1);
        int sown = col[clamped];
        float eown = a_s[sown] + adn;
        eown = (eown > 0.f) ? eown : NEG_SLOPE * eown;
        float pown = (k_idx < end) ? __expf(eown) : 0.f;
        #pragma unroll
        for (int k = 0; k < 8; ++k) {
            int  sk = __shfl(sown, egrp + k);
            float pk = __shfl(pown, egrp + k);
            den += pk;
            acc = fmaf(pk, __bfloat162float(h[(size_t)sk * FOUT + f]), acc);
        }
    }
    float v = acc / den + bias[f];             // self-loop guarantees den > 0
    if (do_relu) v = fmaxf(v, 0.f);
    outp[(size_t)node * FOUT + f] = v;
}

extern "C" void kernel_launch(void* const* d_in, const int* in_sizes, int n_in,
                              void* d_out, int out_size, void* d_ws, size_t ws_size,
                              hipStream_t stream)
{
    const float* x   = (const float*)d_in[0];
    const int* eidx  = (const int*)d_in[1];
    const float* W1  = (const float*)d_in[2];
    const float* as1 = (const float*)d_in[3];
    const float* ad1 = (const float*)d_in[4];
    const float* b1  = (const float*)d_in[5];
    const float* W2  = (const float*)d_in[6];
    const float* as2 = (const float*)d_in[7];
    const float* ad2 = (const float*)d_in[8];
    const float* b2  = (const float*)d_in[9];
    const float* W3  = (const float*)d_in[10];
    const float* as3 = (const float*)d_in[11];
    const float* ad3 = (const float*)d_in[12];
    const float* b3  = (const float*)d_in[13];

    const int fhid = in_sizes[3];        // 64
    const int fin  = in_sizes[2] / fhid; // 128
    const int fo3  = in_sizes[11];       // 32
    const int n    = in_sizes[0] / fin;  // 100000
    const int E    = in_sizes[1] / 2;    // 1,600,000
    const int Etot = E + n;
    const int nsb  = (n + 511) >> 9;     // 196 super-buckets

    const int* esrc = eidx;
    const int* edst = eidx + E;

    float* out = (float*)d_out;               // [n, fo3]
    float* h1  = out + (size_t)n * fo3;       // [n, fhid]
    float* h2  = h1 + (size_t)n * fhid;       // [n, fhid]

    // ws: cnt[n] | row[n] | row_end[n] | partials[128] | sbcur[256] |
    //     packed1[Etot] | col[Etot] | h_bf16[n*fhid] | a_s[n] | a_d[n]
    int* cnt      = (int*)d_ws;
    int* row      = cnt + n;
    int* row_end  = row + n;
    int* partials = row_end + n;
    int* sbcur    = partials + 128;
    int* packed1  = sbcur + 256;
    int* col      = packed1 + Etot;
    __hip_bfloat16* h = (__hip_bfloat16*)(col + Etot);
    float* a_s    = (float*)(h + (size_t)n * fhid);
    float* a_d    = a_s + n;

    const int EB = (Etot + 255) / 256;
    const int nb = (n + 1023) / 1024;    // 98 <= 128
    const int nchunks = (Etot + CB_CHUNK - 1) / CB_CHUNK;

    // ---- CSR build (shared by all layers) ----
    hipMemsetAsync(cnt, 0, (size_t)n * 4, stream);
    node_hist<<<EB, 256, 0, stream>>>(edst, E, n, cnt);
    scan_block<<<nb, 1024, 0, stream>>>(cnt, n, row, partials);
    scan_partials<<<1, 128, 0, stream>>>(partials, nb);
    scan_add<<<nb, 1024, 0, stream>>>(row, n, partials, cnt, row_end);
    init_sbcur<<<(nsb + 255) / 256, 256, 0, stream>>>(row, n, nsb, sbcur);
    chunk_bin<<<nchunks, 256, 0, stream>>>(esrc, edst, E, n, nsb, sbcur, packed1);
    sb_sort<<<nsb, 256, 0, stream>>>(row, packed1, col, n, Etot);

    const int NLB64  = (n + 63) / 64;
    const int NLB128 = (n + 127) / 128;
    const int AGG64 = (n + 3) / 4;
    const int AGG32 = (n + 7) / 8;

    // ---- Layer 1: x[128] -> h1[64], relu ----
    node_linear<128, 64><<<NLB64, 256, 0, stream>>>(x, W1, as1, ad1, h, a_s, a_d, n);
    gat_aggregate<64><<<AGG64, 256, 0, stream>>>(row_end, col, a_s, a_d, h, b1, h1, n, 1);

    // ---- Layer 2: h1[64] -> h2[64], relu ----
    node_linear<64, 64><<<NLB64, 256, 0, stream>>>(h1, W2, as2, ad2, h, a_s, a_d, n);
    gat_aggregate<64><<<AGG64, 256, 0, stream>>>(row_end, col, a_s, a_d, h, b2, h2, n, 1);

    // ---- Layer 3: h2[64] -> out[32], no relu ----
    node_linear<64, 32><<<NLB128, 256, 0, stream>>>(h2, W3, as3, ad3, h, a_s, a_d, n);
    gat_aggregate<32><<<AGG32, 256, 0, stream>>>(row_end, col, a_s, a_d, h, b3, out, n, 0);
}

// Round 15
// 323.906 us; speedup vs baseline: 2.3358x; 1.0903x over previous
//
#include <hip/hip_runtime.h>
#include <hip/hip_bf16.h>

#define NEG_SLOPE 0.2f

__device__ __forceinline__ unsigned short bf16bits(float f) {
    __hip_bfloat16 t = __float2bfloat16(f);
    return *reinterpret_cast<unsigned short*>(&t);
}

// Tiled GEMM node transform: block of 256 threads computes a [NB x FOUT] tile
// of h = x@W. Each thread: 4 nodes x 4 features in registers (16 FMA per k).
template <int FIN, int FOUT>
__global__ __launch_bounds__(256) void node_linear(
    const float* __restrict__ x, const float* __restrict__ W,
    const float* __restrict__ att_s, const float* __restrict__ att_d,
    __hip_bfloat16* __restrict__ h, float* __restrict__ a_s, float* __restrict__ a_d, int n)
{
    constexpr int FG = FOUT / 4;          // feature groups (4 features each)
    constexpr int NG = 256 / FG;          // node groups (4 nodes each)
    constexpr int NB = NG * 4;            // nodes per block
    constexpr int RS = FIN + 4;           // padded row stride
    __shared__ float xs[NB * RS];

    const int tid = threadIdx.x;
    const int base = blockIdx.x * NB;

    constexpr int CNT = NB * FIN / 4 / 256;
    #pragma unroll
    for (int i = 0; i < CNT; ++i) {
        int f4 = tid + 256 * i;
        int node = f4 / (FIN / 4);
        int kk = f4 % (FIN / 4);
        float4 v = make_float4(0.f, 0.f, 0.f, 0.f);
        if (base + node < n) v = *(const float4*)(x + (size_t)(base + node) * FIN + kk * 4);
        *(float4*)(xs + node * RS + kk * 4) = v;
    }
    __syncthreads();

    const int fg = tid % FG;
    const int ng = tid / FG;
    const float* wp = W + fg * 4;
    const float* xr0 = xs + (ng * 4 + 0) * RS;
    const float* xr1 = xs + (ng * 4 + 1) * RS;
    const float* xr2 = xs + (ng * 4 + 2) * RS;
    const float* xr3 = xs + (ng * 4 + 3) * RS;

    float a00=0,a01=0,a02=0,a03=0, a10=0,a11=0,a12=0,a13=0;
    float a20=0,a21=0,a22=0,a23=0, a30=0,a31=0,a32=0,a33=0;
    #pragma unroll 4
    for (int k = 0; k < FIN; ++k) {
        float4 w = *(const float4*)(wp + (size_t)k * FOUT);
        float x0 = xr0[k], x1 = xr1[k], x2 = xr2[k], x3 = xr3[k];
        a00 = fmaf(x0, w.x, a00); a01 = fmaf(x0, w.y, a01);
        a02 = fmaf(x0, w.z, a02); a03 = fmaf(x0, w.w, a03);
        a10 = fmaf(x1, w.x, a10); a11 = fmaf(x1, w.y, a11);
        a12 = fmaf(x1, w.z, a12); a13 = fmaf(x1, w.w, a13);
        a20 = fmaf(x2, w.x, a20); a21 = fmaf(x2, w.y, a21);
        a22 = fmaf(x2, w.z, a22); a23 = fmaf(x2, w.w, a23);
        a30 = fmaf(x3, w.x, a30); a31 = fmaf(x3, w.y, a31);
        a32 = fmaf(x3, w.z, a32); a33 = fmaf(x3, w.w, a33);
    }

    const float4 ats = *(const float4*)(att_s + fg * 4);
    const float4 atd = *(const float4*)(att_d + fg * 4);
    float acc[4][4] = {{a00,a01,a02,a03},{a10,a11,a12,a13},
                       {a20,a21,a22,a23},{a30,a31,a32,a33}};
    #pragma unroll
    for (int i = 0; i < 4; ++i) {
        int node = base + ng * 4 + i;
        float ps = acc[i][0]*ats.x + acc[i][1]*ats.y + acc[i][2]*ats.z + acc[i][3]*ats.w;
        float pd = acc[i][0]*atd.x + acc[i][1]*atd.y + acc[i][2]*atd.z + acc[i][3]*atd.w;
        #pragma unroll
        for (int o = FG / 2; o > 0; o >>= 1) {
            ps += __shfl_xor(ps, o);
            pd += __shfl_xor(pd, o);
        }
        if (fg == 0 && node < n) { a_s[node] = ps; a_d[node] = pd; }
        if (node < n) {
            unsigned w0 = (unsigned)bf16bits(acc[i][0]) | ((unsigned)bf16bits(acc[i][1]) << 16);
            unsigned w1 = (unsigned)bf16bits(acc[i][2]) | ((unsigned)bf16bits(acc[i][3]) << 16);
            uint2 pk; pk.x = w0; pk.y = w1;
            *reinterpret_cast<uint2*>(h + (size_t)node * FOUT + fg * 4) = pk;
        }
    }
}

// ---- CSR build: SB hist -> tiny scan -> per-chunk SB bin -> per-SB local
// sort (node offsets derived LOCALLY per SB; no global node histogram/scan).
// Super-bucket (SB) = 512 consecutive dst nodes. packed = (dst&511)<<17 | src.

// Per-block LDS histogram of SBs; <=196 global atomics per block.
__global__ __launch_bounds__(256) void sb_hist(
    const int* __restrict__ edst, int E, int n, int* __restrict__ sbhist)
{
    __shared__ int lh[256];
    const int tid = threadIdx.x;
    lh[tid] = 0;
    __syncthreads();
    const int Etot = E + n;
    const int stride = gridDim.x * 256;
    for (int i = blockIdx.x * 256 + tid; i < Etot; i += stride) {
        int d = (i < E) ? edst[i] : i - E;   // appended self-loops
        atomicAdd(&lh[d >> 9], 1);
    }
    __syncthreads();
    if (lh[tid] > 0) atomicAdd(&sbhist[tid], lh[tid]);
}

// Single block: exclusive scan of sbhist -> sbbase[0..nsb] (sbbase[nsb]=Etot),
// seed sbcur = sbbase.
__global__ __launch_bounds__(256) void sb_scan(
    const int* __restrict__ sbhist, int nsb, int Etot,
    int* __restrict__ sbbase, int* __restrict__ sbcur)
{
    __shared__ int buf[256];
    const int tid = threadIdx.x;
    int v = (tid < nsb) ? sbhist[tid] : 0;
    buf[tid] = v;
    __syncthreads();
    for (int off = 1; off < 256; off <<= 1) {
        int t = (tid >= off) ? buf[tid - off] : 0;
        __syncthreads();
        buf[tid] += t;
        __syncthreads();
    }
    if (tid < nsb) {
        int ex = buf[tid] - v;
        sbbase[tid] = ex;
        sbcur[tid] = ex;
    }
    if (tid == 0) sbbase[nsb] = Etot;
}

// Stateless per-chunk SB binning: each block owns CHUNK edges. (1) stage to
// LDS + LDS histogram of 196 SBs; (2) ONE global atomicAdd per non-empty SB
// reserves a contiguous run; (3) scatter from LDS to the reserved run.
#define CB_CHUNK 4096
#define CB_NSB_MAX 256
__global__ __launch_bounds__(256) void chunk_bin(
    const int* __restrict__ esrc, const int* __restrict__ edst, int E, int n,
    int nsb, int* __restrict__ sbcur, int* __restrict__ packed1)
{
    __shared__ int pk[CB_CHUNK];
    __shared__ unsigned short sbv[CB_CHUNK];
    __shared__ int hist[CB_NSB_MAX];
    __shared__ int gbase[CB_NSB_MAX];
    const int tid = threadIdx.x;
    const int i0 = blockIdx.x * CB_CHUNK;
    const int Etot = E + n;

    hist[tid] = 0;
    __syncthreads();

    for (int j = tid; j < CB_CHUNK; j += 256) {
        int i = i0 + j;
        if (i < Etot) {
            int s, d;
            if (i < E) { s = esrc[i]; d = edst[i]; }
            else       { s = d = i - E; }          // appended self-loops
            int sb = d >> 9;
            pk[j] = ((d & 511) << 17) | s;
            sbv[j] = (unsigned short)sb;
            atomicAdd(&hist[sb], 1);
        } else {
            sbv[j] = 0xFFFFu;
        }
    }
    __syncthreads();

    if (tid < nsb && hist[tid] > 0)
        gbase[tid] = atomicAdd(&sbcur[tid], hist[tid]);
    hist[tid] = 0;                         // reuse as local cursor
    __syncthreads();

    for (int j = tid; j < CB_CHUNK; j += 256) {
        unsigned short sb = sbv[j];
        if (sb != 0xFFFFu) {
            int pos = gbase[sb] + atomicAdd(&hist[sb], 1);
            packed1[pos] = pk[j];
        }
    }
}

// One block per SB: LDS histogram + 512-entry LDS scan of its own nodes
// (from its L2-local packed region), write row_end (coalesced), then exact
// per-node scatter into the block-owned contiguous col region.
__global__ __launch_bounds__(256) void sb_sort2(
    const int* __restrict__ sbbase, const int* __restrict__ packed1,
    int* __restrict__ col, int* __restrict__ row_end, int n)
{
    const int sb = blockIdx.x;
    const int node0 = sb << 9;
    const int lo = sbbase[sb];
    const int hi = sbbase[sb + 1];
    const int tid = threadIdx.x;
    __shared__ int c[512];    // counts -> cursors
    __shared__ int sc[512];   // scan buffer
    c[tid] = 0; c[tid + 256] = 0;
    __syncthreads();
    for (int j = lo + tid; j < hi; j += 256)
        atomicAdd(&c[((unsigned)packed1[j]) >> 17], 1);
    __syncthreads();
    sc[tid] = c[tid]; sc[tid + 256] = c[tid + 256];
    __syncthreads();
    // inclusive Hillis-Steele over 512 (each thread owns 2 slots)
    for (int off = 1; off < 512; off <<= 1) {
        int i0 = tid, i1 = tid + 256;
        int v0 = (i0 >= off) ? sc[i0 - off] : 0;
        int v1 = (i1 >= off) ? sc[i1 - off] : 0;
        __syncthreads();
        sc[i0] += v0; sc[i1] += v1;
        __syncthreads();
    }
    // row_end (global, coalesced) + local exclusive cursors
    #pragma unroll
    for (int q = 0; q < 2; ++q) {
        int i = tid + q * 256;
        int node = node0 + i;
        if (node < n) row_end[node] = lo + sc[i];
        c[i] = lo + sc[i] - c[i];          // exclusive start cursor
    }
    __syncthreads();
    for (int j = lo + tid; j < hi; j += 256) {
        int p = packed1[j];
        int ld = ((unsigned)p) >> 17;
        int pos = atomicAdd(&c[ld], 1);
        col[pos] = p & 0x1FFFF;
    }
}

// ---- Aggregation: FOUT lanes per node. Lane-split scores: lane l computes
// the score for edge j+(l&7) only, then (src,p) broadcast via shuffles.
template <int FOUT>
__global__ __launch_bounds__(256) void gat_aggregate(
    const int* __restrict__ row_end, const int* __restrict__ col,
    const float* __restrict__ a_s, const float* __restrict__ a_d,
    const __hip_bfloat16* __restrict__ h, const float* __restrict__ bias,
    float* __restrict__ outp, int n, int do_relu)
{
    constexpr int NPW = 64 / FOUT;
    const int gwave = (blockIdx.x * 256 + threadIdx.x) >> 6;
    const int lane = threadIdx.x & 63;
    const int node = gwave * NPW + lane / FOUT;
    const int f = lane % FOUT;
    if (node >= n) return;
    const int end = row_end[node];
    const int start = (node == 0) ? 0 : row_end[node - 1];
    const float adn = a_d[node];
    const int egrp = (FOUT == 64) ? 0 : (lane & 32);
    float acc = 0.f, den = 0.f;
    for (int j = start; j < end; j += 8) {
        int k_idx = j + (lane & 7);
        int clamped = (k_idx < end) ? k_idx : (end - 1);
        int sown = col[clamped];
        float eown = a_s[sown] + adn;
        eown = (eown > 0.f) ? eown : NEG_SLOPE * eown;
        float pown = (k_idx < end) ? __expf(eown) : 0.f;
        #pragma unroll
        for (int k = 0; k < 8; ++k) {
            int  sk = __shfl(sown, egrp + k);
            float pk = __shfl(pown, egrp + k);
            den += pk;
            acc = fmaf(pk, __bfloat162float(h[(size_t)sk * FOUT + f]), acc);
        }
    }
    float v = acc / den + bias[f];             // self-loop guarantees den > 0
    if (do_relu) v = fmaxf(v, 0.f);
    outp[(size_t)node * FOUT + f] = v;
}

extern "C" void kernel_launch(void* const* d_in, const int* in_sizes, int n_in,
                              void* d_out, int out_size, void* d_ws, size_t ws_size,
                              hipStream_t stream)
{
    const float* x   = (const float*)d_in[0];
    const int* eidx  = (const int*)d_in[1];
    const float* W1  = (const float*)d_in[2];
    const float* as1 = (const float*)d_in[3];
    const float* ad1 = (const float*)d_in[4];
    const float* b1  = (const float*)d_in[5];
    const float* W2  = (const float*)d_in[6];
    const float* as2 = (const float*)d_in[7];
    const float* ad2 = (const float*)d_in[8];
    const float* b2  = (const float*)d_in[9];
    const float* W3  = (const float*)d_in[10];
    const float* as3 = (const float*)d_in[11];
    const float* ad3 = (const float*)d_in[12];
    const float* b3  = (const float*)d_in[13];

    const int fhid = in_sizes[3];        // 64
    const int fin  = in_sizes[2] / fhid; // 128
    const int fo3  = in_sizes[11];       // 32
    const int n    = in_sizes[0] / fin;  // 100000
    const int E    = in_sizes[1] / 2;    // 1,600,000
    const int Etot = E + n;
    const int nsb  = (n + 511) >> 9;     // 196 super-buckets

    const int* esrc = eidx;
    const int* edst = eidx + E;

    float* out = (float*)d_out;               // [n, fo3]
    float* h1  = out + (size_t)n * fo3;       // [n, fhid]
    float* h2  = h1 + (size_t)n * fhid;       // [n, fhid]

    // ws: sbhist[256] | sbbase[260] | sbcur[256] | row_end[n] |
    //     packed1[Etot] | col[Etot] | h_bf16[n*fhid] | a_s[n] | a_d[n]
    int* sbhist   = (int*)d_ws;
    int* sbbase   = sbhist + 256;
    int* sbcur    = sbbase + 260;
    int* row_end  = sbcur + 256;
    int* packed1  = row_end + n;
    int* col      = packed1 + Etot;
    __hip_bfloat16* h = (__hip_bfloat16*)(col + Etot);
    float* a_s    = (float*)(h + (size_t)n * fhid);
    float* a_d    = a_s + n;

    const int nchunks = (Etot + CB_CHUNK - 1) / CB_CHUNK;

    // ---- CSR build (shared by all layers) ----
    hipMemsetAsync(sbhist, 0, 256 * 4, stream);
    sb_hist<<<1024, 256, 0, stream>>>(edst, E, n, sbhist);
    sb_scan<<<1, 256, 0, stream>>>(sbhist, nsb, Etot, sbbase, sbcur);
    chunk_bin<<<nchunks, 256, 0, stream>>>(esrc, edst, E, n, nsb, sbcur, packed1);
    sb_sort2<<<nsb, 256, 0, stream>>>(sbbase, packed1, col, row_end, n);

    const int NLB64  = (n + 63) / 64;
    const int NLB128 = (n + 127) / 128;
    const int AGG64 = (n + 3) / 4;
    const int AGG32 = (n + 7) / 8;

    // ---- Layer 1: x[128] -> h1[64], relu ----
    node_linear<128, 64><<<NLB64, 256, 0, stream>>>(x, W1, as1, ad1, h, a_s, a_d, n);
    gat_aggregate<64><<<AGG64, 256, 0, stream>>>(row_end, col, a_s, a_d, h, b1, h1, n, 1);

    // ---- Layer 2: h1[64] -> h2[64], relu ----
    node_linear<64, 64><<<NLB64, 256, 0, stream>>>(h1, W2, as2, ad2, h, a_s, a_d, n);
    gat_aggregate<64><<<AGG64, 256, 0, stream>>>(row_end, col, a_s, a_d, h, b2, h2, n, 1);

    // ---- Layer 3: h2[64] -> out[32], no relu ----
    node_linear<64, 32><<<NLB128, 256, 0, stream>>>(h2, W3, as3, ad3, h, a_s, a_d, n);
    gat_aggregate<32><<<AGG32, 256, 0, stream>>>(row_end, col, a_s, a_d, h, b3, out, n, 0);
}